// Round 7
// baseline (5185.659 us; speedup 1.0000x reference)
//
#include <hip/hip_runtime.h>
#include <hip/hip_bf16.h>

// TreeLSTM (child-sum, complete binary tree, DEPTH=8) on MI355X.
// Round 7: persistent mega-kernel with a SOFTWARE grid barrier (plain
// <<<512,256>>> launch — cooperative launch is incompatible with this
// harness's graph capture, proven R5/R6). Co-residency guaranteed by
// __launch_bounds__(256,2): VGPR<=256 -> >=2 blocks/CU -> 512 co-resident.
// Barrier: epoch counter in ws (hipMemsetAsync-zeroed in-stream), AGENT-scope
// release add + acquire spin + threadfence. Math identical to R4/R6.

#define Hdim 768
#define NBLK 512

typedef __hip_bfloat16 bf16;
typedef __attribute__((ext_vector_type(8))) short short8;
typedef __attribute__((ext_vector_type(4))) float floatx4;

struct P {
    const float *x, *Wioux, *b_ioux, *Wiouh, *Wfx, *b_fx, *Wfh, *b_fh;
    const float *ln_c_g, *ln_c_b, *ln_h_g, *ln_h_b, *Wout, *b_out;
    float* out;
    unsigned int* barrier_cnt;
    bf16 *W_cat, *Wfh_bf, *Wout_bf;
    float* b_cat;
    bf16 *leafA, *A6, *A5, *Cbuf, *hA, *hB;
};

__device__ inline float b2f(unsigned short u) {
    union { unsigned int i; float f; } v; v.i = ((unsigned int)u) << 16; return v.f;
}
__device__ inline float b2f(bf16 h) { return b2f(*(unsigned short*)&h); }
__device__ inline unsigned short f2bu(float f) {
    bf16 h = __float2bfloat16(f);
    return *(unsigned short*)&h;
}
__device__ inline ushort4 cvt4(float4 v) {
    ushort4 o; o.x = f2bu(v.x); o.y = f2bu(v.y); o.z = f2bu(v.z); o.w = f2bu(v.w);
    return o;
}
__device__ inline float sigf(float x) { return 1.f / (1.f + __expf(-x)); }
__device__ inline float tanh_fast(float x) { return 2.f / (1.f + __expf(-2.f * x)) - 1.f; }

// ---------------- software grid barrier ----------------
// target = epoch*NBLK. Release add makes prior writes visible (agent scope =
// LLC coherence point, valid across XCDs); acquire spin + threadfence
// invalidates local L1/L2 before post-barrier reads. Watchdog cap converts a
// (theoretically impossible) deadlock into a loud wrong-answer, not a hang.
__device__ inline void sync_grid(unsigned int* cnt, unsigned int target) {
    __syncthreads();
    if (threadIdx.x == 0) {
        __threadfence();
        __hip_atomic_fetch_add(cnt, 1u, __ATOMIC_RELEASE, __HIP_MEMORY_SCOPE_AGENT);
        long spins = 0;
        while (__hip_atomic_load(cnt, __ATOMIC_ACQUIRE, __HIP_MEMORY_SCOPE_AGENT)
               < target) {
            __builtin_amdgcn_s_sleep(2);
            if (++spins > (1L << 22)) break;   // ~0.2s watchdog
        }
        __threadfence();
    }
    __syncthreads();
}

// ---------------- prep body (one id = one unit of prep work) ----------------
#define PREP_N 46240
__device__ inline void prep_body(const P& p, int id, int t) {
    if (id < 24576) {                       // W_cat rows
        const int l = id / 3072, g = id % 3072;
        bf16* dst = p.W_cat + (long)id * 1536;
        for (int c = t; c < 384; c += 256) {
            const int k2 = c << 2;
            float4 v;
            if (g < 2304) {
                const float* src = (k2 < 768)
                    ? p.Wioux + ((long)l * 2304 + g) * 768 + k2
                    : p.Wiouh + ((long)l * 2304 + g) * 768 + (k2 - 768);
                v = *(const float4*)src;
            } else if (k2 < 768) {
                v = *(const float4*)(p.Wfx + ((long)l * 768 + (g - 2304)) * 768 + k2);
            } else {
                v = make_float4(0.f, 0.f, 0.f, 0.f);
            }
            ((ushort4*)dst)[c] = cvt4(v);
        }
    } else if (id < 29184) {                // Wfh -> bf16
        const long i = (long)(id - 24576) * 256 + t;
        ((ushort4*)p.Wfh_bf)[i] = cvt4(((const float4*)p.Wfh)[i]);
    } else if (id < 29760) {                // Wout -> bf16
        const long i = (long)(id - 29184) * 256 + t;
        ((ushort4*)p.Wout_bf)[i] = cvt4(((const float4*)p.Wout)[i]);
    } else if (id < 29856) {                // b_cat
        const int i = (id - 29760) * 256 + t;
        const int l = i / 3072, g = i % 3072;
        p.b_cat[i] = (g < 2304) ? p.b_ioux[l * 2304 + g]
                                : p.b_fx[l * 768 + (g - 2304)];
    } else if (t < 192) {                   // leaf conversion
        const int m = id - 29856;
        const int b = m >> 7, j = m & 127;
        const float* xr = p.x + ((long)b * 255 + 127 + j) * Hdim;
        ((ushort4*)(p.leafA + (long)m * Hdim))[t] = cvt4(((const float4*)xr)[t]);
    }
}

// ---------------- GEMM tile: 128x128, BK=32, 4 waves, 4x4 16x16x32 MFMA ----
__device__ inline void gemm_tile(
    const bf16* __restrict__ A, int lda,
    const bf16* __restrict__ W, int ldw,
    const float* __restrict__ bias,
    void* __restrict__ Cout, int ldc, int c_fp32, int K,
    int bm, int bn,
    const float* __restrict__ addv, long add_stride,
    bf16* As, bf16* Ws)
{
    const int t = threadIdx.x;
    const int wave = t >> 6, lane = t & 63;
    const long m_blk = (long)bm << 7;
    const long n_blk = (long)bn << 7;

    const int srow = (wave << 5) + (lane >> 2);
    const int sbyte = (lane & 3) << 4;
    const char* gA = (const char*)(A + (m_blk + srow) * (long)lda) + sbyte;
    const char* gW = (const char*)(W + (n_blk + srow) * (long)ldw) + sbyte;
    const long aRow16 = (long)lda * 32;
    const long wRow16 = (long)ldw * 32;
    bf16* lA = As + (wave << 10);
    bf16* lW = Ws + (wave << 10);

    floatx4 zero = {0.f, 0.f, 0.f, 0.f};
    floatx4 acc[4][4];
#pragma unroll
    for (int i = 0; i < 4; i++)
#pragma unroll
        for (int j = 0; j < 4; j++) acc[i][j] = zero;

    const int mrow = (wave & 1) << 6;
    const int ncol = (wave >> 1) << 6;
    const short* AsS = (const short*)As;
    const short* WsS = (const short*)Ws;
    const int fm = lane & 15;
    const int fk = (lane >> 4) << 3;

    for (int k0 = 0; k0 < K; k0 += 32) {
        __builtin_amdgcn_global_load_lds(
            (const __attribute__((address_space(1))) unsigned int*)gA,
            (__attribute__((address_space(3))) unsigned int*)lA, 16, 0, 0);
        __builtin_amdgcn_global_load_lds(
            (const __attribute__((address_space(1))) unsigned int*)(gA + aRow16),
            (__attribute__((address_space(3))) unsigned int*)(lA + 512), 16, 0, 0);
        __builtin_amdgcn_global_load_lds(
            (const __attribute__((address_space(1))) unsigned int*)gW,
            (__attribute__((address_space(3))) unsigned int*)lW, 16, 0, 0);
        __builtin_amdgcn_global_load_lds(
            (const __attribute__((address_space(1))) unsigned int*)(gW + wRow16),
            (__attribute__((address_space(3))) unsigned int*)(lW + 512), 16, 0, 0);
        gA += 64; gW += 64;
        __syncthreads();

        short8 af[4], bfr[4];
#pragma unroll
        for (int i = 0; i < 4; i++) {
            af[i]  = *(const short8*)(AsS + (mrow + i * 16 + fm) * 32 + fk);
            bfr[i] = *(const short8*)(WsS + (ncol + i * 16 + fm) * 32 + fk);
        }
#pragma unroll
        for (int i = 0; i < 4; i++)
#pragma unroll
            for (int j = 0; j < 4; j++)
                acc[i][j] = __builtin_amdgcn_mfma_f32_16x16x32_bf16(
                    af[i], bfr[j], acc[i][j], 0, 0, 0);
        __syncthreads();
    }

    const int crow0 = (lane >> 4) << 2;
    const int ccol = lane & 15;
#pragma unroll
    for (int i = 0; i < 4; i++) {
#pragma unroll
        for (int j = 0; j < 4; j++) {
            const long col = n_blk + ncol + j * 16 + ccol;
            const float bv = bias ? bias[col] : 0.f;
#pragma unroll
            for (int r = 0; r < 4; r++) {
                const long row = m_blk + mrow + i * 16 + crow0 + r;
                float v = acc[i][j][r] + bv;
                if (addv) v += addv[row * add_stride + col];
                if (c_fp32) ((float*)Cout)[row * (long)ldc + col] = v;
                else ((bf16*)Cout)[row * (long)ldc + col] = __float2bfloat16(v);
            }
        }
    }
}

// ---------------- reductions ----------------
__device__ inline void block_reduce4(float& a, float& b, float& c, float& d,
                                     float* s) {
#pragma unroll
    for (int off = 32; off > 0; off >>= 1) {
        a += __shfl_down(a, off, 64);
        b += __shfl_down(b, off, 64);
        c += __shfl_down(c, off, 64);
        d += __shfl_down(d, off, 64);
    }
    const int lane = threadIdx.x & 63, w = threadIdx.x >> 6;
    __syncthreads();
    if (lane == 0) { s[w] = a; s[w + 4] = b; s[w + 8] = c; s[w + 12] = d; }
    __syncthreads();
    a = s[0] + s[1] + s[2] + s[3];
    b = s[4] + s[5] + s[6] + s[7];
    c = s[8] + s[9] + s[10] + s[11];
    d = s[12] + s[13] + s[14] + s[15];
}

// ---------------- pointwise pair (rows 2p,2p+1) ----------------
__device__ inline void pw_pair(
    int pl,
    const bf16* __restrict__ C, int ldc,
    const bf16* __restrict__ fhb,
    const bf16* __restrict__ hprev2,
    const float* __restrict__ x,
    const float* __restrict__ bfh,
    const float* __restrict__ gc, const float* __restrict__ bc,
    const float* __restrict__ gh, const float* __restrict__ bh,
    bf16* __restrict__ hout,
    bf16* __restrict__ Anext,
    int m0, int lp, float* sred)
{
    const bf16* cr0 = C + (long)(2 * pl) * ldc;
    const bf16* cr1 = cr0 + ldc;
    float c0v[3], c1v[3], o0v[3], o1v[3], h0v[3], h1v[3];
    float s0 = 0.f, q0 = 0.f, s1 = 0.f, q1 = 0.f;
#pragma unroll
    for (int tI = 0; tI < 3; tI++) {
        const int j = threadIdx.x + tI * 256;
        const float i0 = sigf(b2f(cr0[j]));
        const float i1 = sigf(b2f(cr1[j]));
        o0v[tI] = b2f(cr0[Hdim + j]);
        o1v[tI] = b2f(cr1[Hdim + j]);
        float c0 = i0 * tanh_fast(b2f(cr0[2 * Hdim + j]));
        float c1 = i1 * tanh_fast(b2f(cr1[2 * Hdim + j]));
        if (fhb) {
            const float bfhj = bfh[j];
            const float fx0 = b2f(cr0[3 * Hdim + j]);
            const float fx1 = b2f(cr1[3 * Hdim + j]);
            const long base = (long)(4 * pl) * Hdim + j;
            const float f00 = sigf(fx0 + b2f(fhb[base]) + bfhj);
            const float f01 = sigf(fx0 + b2f(fhb[base + Hdim]) + bfhj);
            const float f10 = sigf(fx1 + b2f(fhb[base + 2 * Hdim]) + bfhj);
            const float f11 = sigf(fx1 + b2f(fhb[base + 3 * Hdim]) + bfhj);
            c0 += f00 * b2f(hprev2[base]) + f01 * b2f(hprev2[base + Hdim]);
            c1 += f10 * b2f(hprev2[base + 2 * Hdim]) + f11 * b2f(hprev2[base + 3 * Hdim]);
        }
        c0v[tI] = c0; c1v[tI] = c1;
        s0 += c0; q0 += c0 * c0; s1 += c1; q1 += c1 * c1;
    }
    block_reduce4(s0, q0, s1, q1, sred);
    const float m0c = s0 / Hdim, m1c = s1 / Hdim;
    const float r0c = rsqrtf(q0 / Hdim - m0c * m0c + 1e-5f);
    const float r1c = rsqrtf(q1 / Hdim - m1c * m1c + 1e-5f);
    float hs0 = 0.f, hq0 = 0.f, hs1 = 0.f, hq1 = 0.f;
#pragma unroll
    for (int tI = 0; tI < 3; tI++) {
        const int j = threadIdx.x + tI * 256;
        const float cn0 = (c0v[tI] - m0c) * r0c * gc[j] + bc[j];
        const float cn1 = (c1v[tI] - m1c) * r1c * gc[j] + bc[j];
        const float h0 = sigf(o0v[tI]) * tanh_fast(cn0);
        const float h1 = sigf(o1v[tI]) * tanh_fast(cn1);
        h0v[tI] = h0; h1v[tI] = h1;
        hs0 += h0; hq0 += h0 * h0; hs1 += h1; hq1 += h1 * h1;
    }
    block_reduce4(hs0, hq0, hs1, hq1, sred);
    const float mh0 = hs0 / Hdim, mh1 = hs1 / Hdim;
    const float rh0 = rsqrtf(hq0 / Hdim - mh0 * mh0 + 1e-5f);
    const float rh1 = rsqrtf(hq1 / Hdim - mh1 * mh1 + 1e-5f);

    const int pg = m0 / 2 + pl;
    const int b = pg >> lp;
    const int jn = pg & ((1 << lp) - 1);
    const float* xr = x + ((long)b * 255 + (1 << lp) - 1 + jn) * Hdim;
    bf16* arow = Anext + (long)pg * 1536;
#pragma unroll
    for (int tI = 0; tI < 3; tI++) {
        const int j = threadIdx.x + tI * 256;
        const float h0 = (h0v[tI] - mh0) * rh0 * gh[j] + bh[j];
        const float h1 = (h1v[tI] - mh1) * rh1 * gh[j] + bh[j];
        hout[(long)(2 * pl) * Hdim + j] = __float2bfloat16(h0);
        hout[(long)(2 * pl + 1) * Hdim + j] = __float2bfloat16(h1);
        arow[768 + j] = __float2bfloat16(h0 + h1);
        arow[j] = __float2bfloat16(xr[j]);
    }
}

__device__ inline void pw_root(
    int m,
    const bf16* __restrict__ C, int ldc,
    const bf16* __restrict__ fhb, const bf16* __restrict__ hprev,
    const float* __restrict__ bfh,
    const float* __restrict__ gc, const float* __restrict__ bc,
    const float* __restrict__ gh, const float* __restrict__ bh,
    bf16* __restrict__ hout, float* sred)
{
    const bf16* cr = C + (long)m * ldc;
    float cv[3], ov[3], hv[3];
    float ssum = 0.f, ssq = 0.f, d0 = 0.f, d1 = 0.f;
#pragma unroll
    for (int tI = 0; tI < 3; tI++) {
        const int j = threadIdx.x + tI * 256;
        const float i_ = sigf(b2f(cr[j]));
        ov[tI] = b2f(cr[Hdim + j]);
        float c = i_ * tanh_fast(b2f(cr[2 * Hdim + j]));
        const float fx = b2f(cr[3 * Hdim + j]);
        const float bfhj = bfh[j];
        const long base = (long)(2 * m) * Hdim + j;
        const float f0 = sigf(fx + b2f(fhb[base]) + bfhj);
        const float f1 = sigf(fx + b2f(fhb[base + Hdim]) + bfhj);
        c += f0 * b2f(hprev[base]) + f1 * b2f(hprev[base + Hdim]);
        cv[tI] = c; ssum += c; ssq += c * c;
    }
    block_reduce4(ssum, ssq, d0, d1, sred);
    const float mean = ssum / Hdim;
    const float rstd = rsqrtf(ssq / Hdim - mean * mean + 1e-5f);
    float hs = 0.f, hq = 0.f;
#pragma unroll
    for (int tI = 0; tI < 3; tI++) {
        const int j = threadIdx.x + tI * 256;
        const float cn = (cv[tI] - mean) * rstd * gc[j] + bc[j];
        const float h = sigf(ov[tI]) * tanh_fast(cn);
        hv[tI] = h; hs += h; hq += h * h;
    }
    d0 = 0.f; d1 = 0.f;
    block_reduce4(hs, hq, d0, d1, sred);
    const float mh = hs / Hdim;
    const float rh = rsqrtf(hq / Hdim - mh * mh + 1e-5f);
#pragma unroll
    for (int tI = 0; tI < 3; tI++) {
        const int j = threadIdx.x + tI * 256;
        hout[(long)m * Hdim + j] = __float2bfloat16((hv[tI] - mh) * rh * gh[j] + bh[j]);
    }
}

// ---------------- persistent mega-kernel (plain launch) ----------------
__global__ __launch_bounds__(256, 2) void mega(P p)
{
    __shared__ __align__(16) bf16 As[128 * 32];
    __shared__ __align__(16) bf16 Ws[128 * 32];
    __shared__ float sred[16];
    const int GS = gridDim.x;
    const int t = threadIdx.x;
    unsigned int* bar = p.barrier_cnt;
    unsigned int epoch = 0;

    for (int id = blockIdx.x; id < PREP_N; id += GS) prep_body(p, id, t);
    sync_grid(bar, ++epoch * NBLK);

    const int CH = 4096;
    bf16* fhb = p.leafA;

    // leaf level l=7 (M=16384, 4 chunks)
    for (int c = 0; c < 4; c++) {
        const int m0 = c * CH;
        for (int id = blockIdx.x; id < 18 * 32; id += GS)
            gemm_tile(p.leafA + (long)m0 * 768, 768,
                      p.W_cat + 7L * 3072 * 1536, 1536, p.b_cat + 7 * 3072,
                      p.Cbuf, 2304, 0, 768, id / 18, id % 18, nullptr, 0, As, Ws);
        sync_grid(bar, ++epoch * NBLK);
        for (int id = blockIdx.x; id < CH / 2; id += GS)
            pw_pair(id, p.Cbuf, 2304, nullptr, nullptr, p.x, nullptr,
                    p.ln_c_g + 7 * Hdim, p.ln_c_b + 7 * Hdim,
                    p.ln_h_g + 7 * Hdim, p.ln_h_b + 7 * Hdim,
                    p.hA + (long)m0 * Hdim, p.A6, m0, 6, sred);
        sync_grid(bar, ++epoch * NBLK);
    }

    // levels 6..1
    bf16* hp = p.hA; bf16* hc = p.hB;
    bf16* Acur = p.A6; bf16* Anxt = p.A5;
    for (int l = 6; l >= 1; l--) {
        const int M = 128 << l;
        const int Mc = (M < CH) ? M : CH;
        const int nch = M / Mc;
        for (int c = 0; c < nch; c++) {
            const int m0 = c * Mc;
            const int na = 24 * (Mc >> 7);
            const int nb = 6 * ((2 * Mc) >> 7);
            for (int id = blockIdx.x; id < na + nb; id += GS) {
                if (id < na)
                    gemm_tile(Acur + (long)m0 * 1536, 1536,
                              p.W_cat + (long)l * 3072 * 1536, 1536,
                              p.b_cat + l * 3072, p.Cbuf, 3072, 0, 1536,
                              id / 24, id % 24, nullptr, 0, As, Ws);
                else {
                    const int id2 = id - na;
                    gemm_tile(hp + (long)2 * m0 * Hdim, 768,
                              p.Wfh_bf + (long)l * 768 * 768, 768, nullptr,
                              fhb, 768, 0, 768, id2 / 6, id2 % 6,
                              nullptr, 0, As, Ws);
                }
            }
            sync_grid(bar, ++epoch * NBLK);
            for (int id = blockIdx.x; id < Mc / 2; id += GS)
                pw_pair(id, p.Cbuf, 3072, fhb, hp + (long)2 * m0 * Hdim, p.x,
                        p.b_fh + l * Hdim,
                        p.ln_c_g + l * Hdim, p.ln_c_b + l * Hdim,
                        p.ln_h_g + l * Hdim, p.ln_h_b + l * Hdim,
                        hc + (long)m0 * Hdim, Anxt, m0, l - 1, sred);
            sync_grid(bar, ++epoch * NBLK);
        }
        bf16* t1 = hp; hp = hc; hc = t1;
        bf16* t2 = Acur; Acur = Anxt; Anxt = t2;
    }

    // root level l=0
    for (int id = blockIdx.x; id < 24 + 12; id += GS) {
        if (id < 24)
            gemm_tile(Acur, 1536, p.W_cat, 1536, p.b_cat, p.Cbuf, 3072, 0,
                      1536, 0, id, nullptr, 0, As, Ws);
        else {
            const int id2 = id - 24;
            gemm_tile(hp, 768, p.Wfh_bf, 768, nullptr, fhb, 768, 0, 768,
                      id2 / 6, id2 % 6, nullptr, 0, As, Ws);
        }
    }
    sync_grid(bar, ++epoch * NBLK);
    for (int id = blockIdx.x; id < 128; id += GS)
        pw_root(id, p.Cbuf, 3072, fhb, hp, p.b_fh,
                p.ln_c_g, p.ln_c_b, p.ln_h_g, p.ln_h_b, hc, sred);
    sync_grid(bar, ++epoch * NBLK);

    for (int id = blockIdx.x; id < 6; id += GS)
        gemm_tile(hc, 768, p.Wout_bf, 768, p.b_out, p.out, 768, 1, 768,
                  0, id, p.x, 255L * 768, As, Ws);
}

// ---------------- launch ----------------
extern "C" void kernel_launch(void* const* d_in, const int* in_sizes, int n_in,
                              void* d_out, int out_size, void* d_ws, size_t ws_size,
                              hipStream_t stream) {
    (void)in_sizes; (void)n_in; (void)out_size; (void)ws_size;
    P p;
    p.x      = (const float*)d_in[0];
    p.Wioux  = (const float*)d_in[1];
    p.b_ioux = (const float*)d_in[2];
    p.Wiouh  = (const float*)d_in[3];
    p.Wfx    = (const float*)d_in[4];
    p.b_fx   = (const float*)d_in[5];
    p.Wfh    = (const float*)d_in[6];
    p.b_fh   = (const float*)d_in[7];
    p.ln_c_g = (const float*)d_in[8];
    p.ln_c_b = (const float*)d_in[9];
    p.ln_h_g = (const float*)d_in[10];
    p.ln_h_b = (const float*)d_in[11];
    p.Wout   = (const float*)d_in[12];
    p.b_out  = (const float*)d_in[13];
    p.out    = (float*)d_out;

    char* q = (char*)d_ws;                                  // ~212 MB total
    p.barrier_cnt = (unsigned int*)q; q += 256;             // isolated line
    p.W_cat   = (bf16*)q; q += 8L * 3072 * 1536 * 2;
    p.Wfh_bf  = (bf16*)q; q += 8L * 768 * 768 * 2;
    p.Wout_bf = (bf16*)q; q += 768L * 768 * 2;
    p.b_cat   = (float*)q; q += 8L * 3072 * 4;
    p.leafA   = (bf16*)q; q += 16384L * 768 * 2;
    p.A6      = (bf16*)q; q += 8192L * 1536 * 2;
    p.A5      = (bf16*)q; q += 4096L * 1536 * 2;
    p.Cbuf    = (bf16*)q; q += 4096L * 3072 * 2;
    p.hA      = (bf16*)q; q += 16384L * 768 * 2;
    p.hB      = (bf16*)q; q += 8192L * 768 * 2;

    hipMemsetAsync(p.barrier_cnt, 0, 256, stream);
    mega<<<NBLK, 256, 0, stream>>>(p);
}